// Round 10
// baseline (3327.134 us; speedup 1.0000x reference)
//
#include <hip/hip_runtime.h>
#include <hip/hip_bf16.h>
#include <math.h>

#define XKP 1216

typedef unsigned short u16;
typedef short bf16x8 __attribute__((ext_vector_type(8)));
typedef u16 ushort8 __attribute__((ext_vector_type(8)));
typedef float f32x4 __attribute__((ext_vector_type(4)));

static __device__ __forceinline__ float sigmoidf_(float x){ return 1.f/(1.f+expf(-x)); }
static __device__ __forceinline__ u16 f2bf(float x){ __hip_bfloat16 h = __float2bfloat16(x); return *reinterpret_cast<u16*>(&h); }
static __device__ __forceinline__ float bf2f(u16 u){ __hip_bfloat16 h; *reinterpret_cast<u16*>(&h) = u; return __bfloat162float(h); }
static __device__ __forceinline__ float bfb(u16 u){ return __uint_as_float(((unsigned)u) << 16); }

// ---------- grid barrier, 128 blocks: hierarchical arrivals + LOAD polling ----------
// bar[ (blk&7)*16 ] : 8 group counters (64B apart) ; bar[128]: root ; bar[144]: generation
static __device__ __forceinline__ void gridbar(int* bar) {
  __syncthreads();
  if (threadIdx.x == 0) {
    int gen = __hip_atomic_load(&bar[144], __ATOMIC_RELAXED, __HIP_MEMORY_SCOPE_AGENT);
    __threadfence();   // release: my writes visible before arrival
    int old = __hip_atomic_fetch_add(&bar[(blockIdx.x & 7) * 16], 1,
                                     __ATOMIC_RELAXED, __HIP_MEMORY_SCOPE_AGENT);
    if ((old & 15) == 15) {
      int rold = __hip_atomic_fetch_add(&bar[128], 1,
                                        __ATOMIC_RELAXED, __HIP_MEMORY_SCOPE_AGENT);
      if ((rold & 7) == 7)
        __hip_atomic_fetch_add(&bar[144], 1, __ATOMIC_RELAXED, __HIP_MEMORY_SCOPE_AGENT);
    }
    while (__hip_atomic_load(&bar[144], __ATOMIC_RELAXED, __HIP_MEMORY_SCOPE_AGENT) == gen)
      __builtin_amdgcn_s_sleep(4);
    __threadfence();   // acquire: others' writes visible
  }
  __syncthreads();
}

// ---------- generic 32x32 tiled transpose ----------
__global__ __launch_bounds__(256) void k_transpose(const float* __restrict__ in,
                                                   float* __restrict__ out, int R, int C) {
  __shared__ float tile[32][33];
  int c0 = blockIdx.x * 32, r0 = blockIdx.y * 32;
  int tx = threadIdx.x & 31, ty = threadIdx.x >> 5;
  for (int i = 0; i < 32; i += 8) {
    int r = r0 + ty + i, c = c0 + tx;
    tile[ty + i][tx] = (r < R && c < C) ? in[(size_t)r * C + c] : 0.f;
  }
  __syncthreads();
  for (int i = 0; i < 32; i += 8) {
    int c = c0 + ty + i, r = r0 + tx;
    if (c < C && r < R) out[(size_t)c * R + r] = tile[tx][ty + i];
  }
}

// ---------- fp32 -> bf16 ----------
__global__ __launch_bounds__(256) void k_cvt(const float* __restrict__ in,
                                             u16* __restrict__ out, int n) {
  for (int i = blockIdx.x * 256 + threadIdx.x; i < n; i += gridDim.x * 256)
    out[i] = f2bf(in[i]);
}

// ---------- Wcat split hi/lo, gate-interleaved: row n'=d*4+g <- j=g*512+d ----------
__global__ __launch_bounds__(256) void k_wcat_split(const float* __restrict__ W_ih,
                                                    const float* __restrict__ W_hh,
                                                    u16* __restrict__ Whi,
                                                    u16* __restrict__ Wlo) {
  int np = blockIdx.x;
  int d = np >> 2, g = np & 3;
  int j = g * 512 + d;
  for (int c = threadIdx.x; c < XKP; c += 256) {
    float v;
    if (c < 684)        v = W_ih[(size_t)j * 684 + c];
    else if (c < 1196)  v = W_hh[(size_t)j * 512 + (c - 684)];
    else                v = 0.f;
    u16 hi = f2bf(v);
    u16 lo = f2bf(v - bf2f(hi));
    Whi[(size_t)np * XKP + c] = hi;
    Wlo[(size_t)np * XKP + c] = lo;
  }
}

// ---------- objectness mask + top-16 + enc mean ----------
__global__ __launch_bounds__(128) void k_mask(const float* __restrict__ objs,
                                              const float* __restrict__ rcl,
                                              const float* __restrict__ avx,
                                              const float* __restrict__ enc,
                                              float* __restrict__ maskf,
                                              float* __restrict__ encmean,
                                              float* __restrict__ out_mask) {
  int b = blockIdx.x, k = threadIdx.x;
  __shared__ float dsh[128];
  __shared__ float maxd;
  float s0 = objs[(size_t)(b * 128 + k) * 2 + 0];
  float s1 = objs[(size_t)(b * 128 + k) * 2 + 1];
  float mx = fmaxf(s0, s1);
  float e0 = expf(s0 - mx), e1 = expf(s1 - mx);
  float p  = e1 / (e0 + e1);
  bool om  = p > 0.75f;
  float dx = rcl[b * 3 + 0] - avx[(size_t)(b * 128 + k) * 3 + 0];
  float dy = rcl[b * 3 + 1] - avx[(size_t)(b * 128 + k) * 3 + 1];
  float dz = rcl[b * 3 + 2] - avx[(size_t)(b * 128 + k) * 3 + 2];
  float dist = sqrtf(dx * dx + dy * dy + dz * dz);
  float dm = om ? dist : INFINITY;
  dsh[k] = dm;
  __syncthreads();
  float v = dm; int clt = 0, cle = 0;
  for (int j = 0; j < 128; j++) { float o = dsh[j]; clt += (o < v); cle += (o <= v); }
  if (clt < 16 && cle >= 16) maxd = v;
  __syncthreads();
  bool msk = om && (dm <= maxd);
  maskf[b * 128 + k]    = msk ? 1.f : 0.f;
  out_mask[b * 128 + k] = msk ? 1.f : 0.f;
  float s = 0.f;
  for (int kk = 0; kk < 128; kk++) s += enc[(size_t)(b * 128 + kk) * 128 + k];
  encmean[b * 128 + k] = s * (1.f / 128.f);
}

// ---------- h0/c0 init (+ zero the grid barrier) ----------
__global__ __launch_bounds__(512) void k_init(const float* __restrict__ encm,
                                              const float* __restrict__ rof,
                                              const float* __restrict__ wihT,
                                              const float* __restrict__ wicT,
                                              const float* __restrict__ bh,
                                              const float* __restrict__ bc,
                                              float* __restrict__ h, float* __restrict__ c,
                                              int* __restrict__ bar) {
  int b = blockIdx.x, d = threadIdx.x;
  if (b == 0 && d < 256) bar[d] = 0;
  __shared__ float xin[384];
  if (d < 128) xin[d] = encm[b * 128 + d];
  else if (d < 384) xin[d] = rof[(size_t)b * 256 + (d - 128)];
  __syncthreads();
  float ah = bh[d], ac = bc[d];
  for (int i = 0; i < 384; i++) {
    float x = xin[i];
    ah += x * wihT[(size_t)i * 512 + d];
    ac += x * wicT[(size_t)i * 512 + d];
  }
  size_t idx = (size_t)b * 512 + d;
  h[idx] = ah;
  c[idx] = ac;
}

// ---------- att1 via MFMA -> bf16 out ----------
__global__ __launch_bounds__(256) void k_att1m(const u16* __restrict__ enc16,
                                               const u16* __restrict__ We16,
                                               const float* __restrict__ b_enc,
                                               u16* __restrict__ att1b) {
  int w = threadIdx.x >> 6, lane = threadIdx.x & 63;
  int gw = blockIdx.x * 4 + w;
  int nt = gw & 15, mt = gw >> 4;
  int m0 = mt * 32, n0 = nt * 32;
  int rc = lane & 15, kb = lane >> 4;
  const bf16x8* a0 = (const bf16x8*)(enc16 + (size_t)(m0 + rc) * 128) + kb;
  const bf16x8* a1 = (const bf16x8*)(enc16 + (size_t)(m0 + 16 + rc) * 128) + kb;
  const bf16x8* b0 = (const bf16x8*)(We16 + (size_t)(n0 + rc) * 128) + kb;
  const bf16x8* b1 = (const bf16x8*)(We16 + (size_t)(n0 + 16 + rc) * 128) + kb;
  f32x4 z = {0.f, 0.f, 0.f, 0.f};
  f32x4 acc00 = z, acc01 = z, acc10 = z, acc11 = z;
#pragma unroll
  for (int kk = 0; kk < 4; kk++) {
    bf16x8 av0 = a0[kk * 4], av1 = a1[kk * 4];
    bf16x8 bv0 = b0[kk * 4], bv1 = b1[kk * 4];
    acc00 = __builtin_amdgcn_mfma_f32_16x16x32_bf16(av0, bv0, acc00, 0, 0, 0);
    acc01 = __builtin_amdgcn_mfma_f32_16x16x32_bf16(av0, bv1, acc01, 0, 0, 0);
    acc10 = __builtin_amdgcn_mfma_f32_16x16x32_bf16(av1, bv0, acc10, 0, 0, 0);
    acc11 = __builtin_amdgcn_mfma_f32_16x16x32_bf16(av1, bv1, acc11, 0, 0, 0);
  }
  int col = lane & 15, rbase = (lane >> 4) * 4;
#pragma unroll
  for (int r = 0; r < 4; r++) {
    int r0g = m0 + rbase + r;
    att1b[(size_t)r0g * 512 + n0 + col]             = f2bf(acc00[r] + b_enc[n0 + col]);
    att1b[(size_t)r0g * 512 + n0 + 16 + col]        = f2bf(acc01[r] + b_enc[n0 + 16 + col]);
    att1b[(size_t)(r0g + 16) * 512 + n0 + col]      = f2bf(acc10[r] + b_enc[n0 + col]);
    att1b[(size_t)(r0g + 16) * 512 + n0 + 16 + col] = f2bf(acc11[r] + b_enc[n0 + 16 + col]);
  }
}

// ================= persistent decode kernel (128 blocks x 512 thr) =================
struct DecArgs {
  const u16*   att1b;     // [16384,512] bf16
  const float* wdT;       // [512,512]
  const float* b_dec;
  const float* wfull;
  const float* bfull;
  const u16*   enc16;     // [128,128,128] bf16
  const float* maskf;
  const float* wfbT;      // [512,128]
  const float* b_fb;
  const float* rof;
  const float* embt;
  const float* iemb;
  const int*   lidx;
  const int*   llen;
  const u16*   WcatHi;    // [2048,1216] n'=d*4+g
  const u16*   WcatLo;
  const float* b_ih;
  const float* b_hh;
  const u16*   Wfc16;     // [4000,512]
  const float* b_fc;
  float* hbuf; float* cbuf;
  u16* Xhi; u16* Xlo;     // [128,1216]
  u16* hball;             // [32,128,512] bf16
  float* predsT;          // [32,128,4000]
  float* out_alpha;
  float* out_pred;
  int* bar;
  int direct;
};

__global__ __launch_bounds__(512) void k_decode(DecArgs A) {
  const int tid = threadIdx.x;
  const int w = tid >> 6, lane = tid & 63;
  const int rc = lane & 15, kb = lane >> 4;
  const int b = blockIdx.x;                       // this block's batch row
  const int np = (blockIdx.x & 7) * 16 + (blockIdx.x >> 3);  // this block's gates n'-tile

  __shared__ float hs[512], a2s[512], wf[512];
  __shared__ float attk[128], alph[128], gts[128], awes[128];
  __shared__ float red1[8], red2[8];
  __shared__ float ttile[32][33];

  for (int t = 0; t < 32; ++t) {
    // ---------- P2: per-b attention ----------
    hs[tid] = A.hbuf[(size_t)b * 512 + tid];
    wf[tid] = A.wfull[tid];
    __syncthreads();
    // att2[a] = h . W_dec[a,:] + b_dec (4-acc unrolled)
    {
      float ac0 = 0.f, ac1 = 0.f, ac2 = 0.f, ac3 = 0.f;
      for (int i = 0; i < 512; i += 4) {
        ac0 += hs[i + 0] * A.wdT[(size_t)(i + 0) * 512 + tid];
        ac1 += hs[i + 1] * A.wdT[(size_t)(i + 1) * 512 + tid];
        ac2 += hs[i + 2] * A.wdT[(size_t)(i + 2) * 512 + tid];
        ac3 += hs[i + 3] * A.wdT[(size_t)(i + 3) * 512 + tid];
      }
      a2s[tid] = (ac0 + ac1) + (ac2 + ac3) + A.b_dec[tid];
    }
    __syncthreads();
    // att[k] = relu(att1+att2).wfull   (4 threads per k, bf16 att1)
    int k = tid >> 2, j = tid & 3;
    {
      const ushort8* a1 = (const ushort8*)(A.att1b + (size_t)(b * 128 + k) * 512 + j * 128);
      float s = 0.f;
#pragma unroll 2
      for (int i = 0; i < 16; i++) {
        ushort8 v = a1[i];
        int base = j * 128 + i * 8;
#pragma unroll
        for (int e = 0; e < 8; e++)
          s += fmaxf(bfb(v[e]) + a2s[base + e], 0.f) * wf[base + e];
      }
      s += __shfl_xor(s, 1);
      s += __shfl_xor(s, 2);
      if (j == 0) attk[k] = s + A.bfull[0];
    }
    __syncthreads();
    // masked softmax over K=128 (tid<128)
    float mk = 0.f, av = 0.f;
    if (tid < 128) { mk = A.maskf[b * 128 + tid]; av = attk[tid]; }
    float nv = (tid < 128 && mk != 0.f) ? av : -INFINITY;
    float wm = nv;
#pragma unroll
    for (int o = 32; o > 0; o >>= 1) wm = fmaxf(wm, __shfl_xor(wm, o));
    if (tid < 128 && lane == 0) red1[w] = wm;
    __syncthreads();
    float m = fmaxf(red1[0], red1[1]);
    float e = (tid < 128 && mk != 0.f) ? expf(av - m) : 0.f;
    float sr = e;
#pragma unroll
    for (int o = 32; o > 0; o >>= 1) sr += __shfl_xor(sr, o);
    if (tid < 128 && lane == 0) red2[w] = sr;
    __syncthreads();
    float dsum = red2[0] + red2[1];
    float alpha = (dsum > 0.f) ? e / fmaxf(dsum, 1e-30f) : 0.f;
    int active = t < A.llen[b];
    if (tid < 128) {
      alph[tid] = alpha;
      A.out_alpha[((size_t)b * 32 + t) * 128 + tid] = active ? alpha : 0.f;
    }
    __syncthreads();
    // gate[v] then awe[v] (4 threads per v)
    {
      int v = tid >> 2;
      float g = 0.f;
      for (int ii = 0; ii < 128; ii++) {
        int i = j * 128 + ii;
        g += hs[i] * A.wfbT[(size_t)i * 128 + v];
      }
      g += __shfl_xor(g, 1);
      g += __shfl_xor(g, 2);
      float gate = sigmoidf_(g + A.b_fb[v]);
      float aw = 0.f;
      for (int kk = j * 32; kk < j * 32 + 32; kk++)
        aw += alph[kk] * bfb(A.enc16[(size_t)(b * 128 + kk) * 128 + v]);
      aw += __shfl_xor(aw, 1);
      aw += __shfl_xor(aw, 2);
      if (j == 0) awes[v] = aw * gate;
    }
    __syncthreads();
    // X row b -> bf16 hi/lo
    const float* esrc = (t == 0) ? A.iemb : (A.embt + (size_t)A.lidx[b * 32 + (t - 1)] * 300);
    for (int c = tid; c < XKP; c += 512) {
      float val;
      if (c < 300)       val = esrc[c];
      else if (c < 428)  val = awes[c - 300];
      else if (c < 684)  val = A.rof[(size_t)b * 256 + (c - 428)];
      else if (c < 1196) val = hs[c - 684];
      else               val = 0.f;
      u16 hi = f2bf(val);
      A.Xhi[(size_t)b * XKP + c] = hi;
      A.Xlo[(size_t)b * XKP + c] = f2bf(val - bf2f(hi));
    }
    gridbar(A.bar);

    // ---------- P3: gates GEMM + LSTM. Block owns n'-tile np; wave w owns m-tile w ----------
    {
      int m0 = w * 16, n0 = np * 16;
      const bf16x8* aHi = (const bf16x8*)(A.Xhi + (size_t)(m0 + rc) * XKP) + kb;
      const bf16x8* aLo = (const bf16x8*)(A.Xlo + (size_t)(m0 + rc) * XKP) + kb;
      const bf16x8* bHi = (const bf16x8*)(A.WcatHi + (size_t)(n0 + rc) * XKP) + kb;
      const bf16x8* bLo = (const bf16x8*)(A.WcatLo + (size_t)(n0 + rc) * XKP) + kb;
      f32x4 acc = {0.f, 0.f, 0.f, 0.f};
#pragma unroll 2
      for (int kk = 0; kk < 38; kk++) {
        bf16x8 ah = aHi[kk * 4], al = aLo[kk * 4];
        bf16x8 bh = bHi[kk * 4], bl = bLo[kk * 4];
        acc = __builtin_amdgcn_mfma_f32_16x16x32_bf16(ah, bh, acc, 0, 0, 0);
        acc = __builtin_amdgcn_mfma_f32_16x16x32_bf16(al, bh, acc, 0, 0, 0);
        acc = __builtin_amdgcn_mfma_f32_16x16x32_bf16(ah, bl, acc, 0, 0, 0);
      }
      // LSTM via intra-wave shfl: lanes 4q..4q+3 hold gates 0..3 of d=np*4+q
      int col = lane & 15;
      int d = np * 4 + (col >> 2);
      int baseL = lane & ~3;
#pragma unroll
      for (int r = 0; r < 4; r++) {
        int bb = m0 + (lane >> 4) * 4 + r;
        float g0 = __shfl(acc[r], baseL + 0);
        float g1 = __shfl(acc[r], baseL + 1);
        float g2 = __shfl(acc[r], baseL + 2);
        float g3 = __shfl(acc[r], baseL + 3);
        if ((lane & 3) == 0 && t < A.llen[bb]) {
          float i_ = sigmoidf_(g0 + A.b_ih[d]        + A.b_hh[d]);
          float f_ = sigmoidf_(g1 + A.b_ih[512 + d]  + A.b_hh[512 + d]);
          float gg = tanhf   (g2 + A.b_ih[1024 + d] + A.b_hh[1024 + d]);
          float o_ = sigmoidf_(g3 + A.b_ih[1536 + d] + A.b_hh[1536 + d]);
          size_t idx = (size_t)bb * 512 + d;
          float cn = f_ * A.cbuf[idx] + i_ * gg;
          float hn = o_ * tanhf(cn);
          A.cbuf[idx] = cn;
          A.hbuf[idx] = hn;
          A.hball[((size_t)t * 128 + bb) * 512 + d] = f2bf(hn);
        }
      }
    }
    gridbar(A.bar);
  }

  // ---------- deferred fc: block owns n-tiles {blk, blk+128}; wave w = m-tile w ----------
  for (int nb = blockIdx.x; nb < 250; nb += 128) {
    int n0 = nb * 16;
    const bf16x8* bP = (const bf16x8*)(A.Wfc16 + (size_t)(n0 + rc) * 512) + kb;
    int m0 = w * 16;
    for (int t = 0; t < 32; t++) {
      const bf16x8* aP = (const bf16x8*)(A.hball + ((size_t)t * 128 + m0 + rc) * 512) + kb;
      f32x4 acc = {0.f, 0.f, 0.f, 0.f};
#pragma unroll
      for (int kk = 0; kk < 16; kk++)
        acc = __builtin_amdgcn_mfma_f32_16x16x32_bf16(aP[kk * 4], bP[kk * 4], acc, 0, 0, 0);
      int col = lane & 15, rb = (lane >> 4) * 4;
      int v = n0 + col;
      float bias = A.b_fc[v];
#pragma unroll
      for (int r = 0; r < 4; r++) {
        int bb = m0 + rb + r;
        float val = (t < A.llen[bb]) ? (acc[r] + bias) : 0.f;
        if (A.direct) A.out_pred[((size_t)bb * 4000 + v) * 32 + t] = val;
        else          A.predsT[((size_t)(t * 128 + bb)) * 4000 + v] = val;
      }
    }
  }

  if (!A.direct) {
    gridbar(A.bar);
    // transpose predsT[T,B,V] -> out[B,V,T] : 16000 tiles over 128 blocks
    for (int tile = blockIdx.x; tile < 16000; tile += 128) {
      int vt = tile >> 7, bb = tile & 127;
      int v0 = vt * 32;
      int tx = tid & 31, ty = tid >> 5;   // ty 0..15
      __syncthreads();
      for (int i = 0; i < 32; i += 16) {
        int tt = ty + i;
        ttile[tt][tx] = A.predsT[((size_t)tt * 128 + bb) * 4000 + v0 + tx];
      }
      __syncthreads();
      for (int i = 0; i < 32; i += 16) {
        int v = v0 + ty + i;
        A.out_pred[((size_t)bb * 4000 + v) * 32 + tx] = ttile[tx][ty + i];
      }
    }
  }
}

extern "C" void kernel_launch(void* const* d_in, const int* in_sizes, int n_in,
                              void* d_out, int out_size, void* d_ws, size_t ws_size,
                              hipStream_t stream) {
  (void)in_sizes; (void)n_in; (void)out_size;
  const float* avf   = (const float*)d_in[0];
  const float* rof   = (const float*)d_in[1];
  const float* objs  = (const float*)d_in[2];
  const float* rcl   = (const float*)d_in[3];
  const float* avx   = (const float*)d_in[4];
  const int*   lidx  = (const int*)d_in[5];
  const int*   llen  = (const int*)d_in[6];
  const float* embt  = (const float*)d_in[7];
  const float* iemb  = (const float*)d_in[8];
  const float* W_enc = (const float*)d_in[9];
  const float* b_enc = (const float*)d_in[10];
  const float* W_dec = (const float*)d_in[11];
  const float* b_dec = (const float*)d_in[12];
  const float* wfull = (const float*)d_in[13];
  const float* bfull = (const float*)d_in[14];
  const float* W_ih  = (const float*)d_in[15];
  const float* b_ih  = (const float*)d_in[16];
  const float* W_hh  = (const float*)d_in[17];
  const float* b_hh  = (const float*)d_in[18];
  const float* W_inh = (const float*)d_in[19];
  const float* b_inh = (const float*)d_in[20];
  const float* W_inc = (const float*)d_in[21];
  const float* b_inc = (const float*)d_in[22];
  const float* W_fb  = (const float*)d_in[23];
  const float* b_fb  = (const float*)d_in[24];
  const float* W_fc  = (const float*)d_in[25];
  const float* b_fc  = (const float*)d_in[26];

  float* ws = (float*)d_ws;
  size_t f = 0;
  auto A8 = [&](size_t n) { size_t o = f; f += (n + 63) & ~(size_t)63; return o; };
  u16*   att1b = (u16*)(ws + A8((size_t)16384 * 512 / 2));
  float* wdT   = ws + A8(512 * 512);
  float* wihT  = ws + A8(384 * 512);
  float* wicT  = ws + A8(384 * 512);
  float* wfbT  = ws + A8(512 * 128);
  float* hbuf  = ws + A8(128 * 512);
  float* cbuf  = ws + A8(128 * 512);
  float* maskf = ws + A8(128 * 128);
  float* encm  = ws + A8(128 * 128);
  int*   bar   = (int*)(ws + A8(256));
  u16*   Xhi   = (u16*)(ws + A8((size_t)128 * XKP / 2));
  u16*   Xlo   = (u16*)(ws + A8((size_t)128 * XKP / 2));
  u16*   WcatHi= (u16*)(ws + A8((size_t)2048 * XKP / 2));
  u16*   WcatLo= (u16*)(ws + A8((size_t)2048 * XKP / 2));
  u16*   enc16 = (u16*)(ws + A8((size_t)128 * 128 * 128 / 2));
  u16*   We16  = (u16*)(ws + A8((size_t)512 * 128 / 2));
  u16*   Wfc16 = (u16*)(ws + A8((size_t)4000 * 512 / 2));
  u16*   hball = (u16*)(ws + A8((size_t)32 * 128 * 512 / 2));
  float* predsT= ws + A8((size_t)32 * 128 * 4000);
  bool useT = ws_size >= f * sizeof(float);

  float* out_pred  = (float*)d_out;
  float* out_alpha = out_pred + (size_t)16384000;
  float* out_mask  = out_alpha + (size_t)524288;

  // ---- setup ----
  k_transpose<<<dim3(16, 16), 256, 0, stream>>>(W_dec, wdT, 512, 512);
  k_transpose<<<dim3(12, 16), 256, 0, stream>>>(W_inh, wihT, 512, 384);
  k_transpose<<<dim3(12, 16), 256, 0, stream>>>(W_inc, wicT, 512, 384);
  k_transpose<<<dim3(16, 4),  256, 0, stream>>>(W_fb, wfbT, 128, 512);
  k_wcat_split<<<2048, 256, 0, stream>>>(W_ih, W_hh, WcatHi, WcatLo);
  k_cvt<<<2048, 256, 0, stream>>>(avf, enc16, 128 * 128 * 128);
  k_cvt<<<256,  256, 0, stream>>>(W_enc, We16, 512 * 128);
  k_cvt<<<2048, 256, 0, stream>>>(W_fc, Wfc16, 4000 * 512);
  k_mask<<<128, 128, 0, stream>>>(objs, rcl, avx, avf, maskf, encm, out_mask);
  k_init<<<128, 512, 0, stream>>>(encm, rof, wihT, wicT, b_inh, b_inc, hbuf, cbuf, bar);
  k_att1m<<<2048, 256, 0, stream>>>(enc16, We16, b_enc, att1b);

  // ---- persistent decode (cooperative for co-residency; custom barrier inside) ----
  DecArgs da;
  da.att1b = att1b; da.wdT = wdT; da.b_dec = b_dec;
  da.wfull = wfull; da.bfull = bfull; da.enc16 = enc16; da.maskf = maskf;
  da.wfbT = wfbT; da.b_fb = b_fb; da.rof = rof; da.embt = embt; da.iemb = iemb;
  da.lidx = lidx; da.llen = llen;
  da.WcatHi = WcatHi; da.WcatLo = WcatLo; da.b_ih = b_ih; da.b_hh = b_hh;
  da.Wfc16 = Wfc16; da.b_fc = b_fc;
  da.hbuf = hbuf; da.cbuf = cbuf;
  da.Xhi = Xhi; da.Xlo = Xlo; da.hball = hball;
  da.predsT = predsT; da.out_alpha = out_alpha; da.out_pred = out_pred;
  da.bar = bar;
  da.direct = useT ? 0 : 1;
  void* kargs[] = { (void*)&da };
  hipLaunchCooperativeKernel((const void*)k_decode, dim3(128), dim3(512), kargs, 0, stream);
}

// Round 11
// 2276.223 us; speedup vs baseline: 1.4617x; 1.4617x over previous
//
#include <hip/hip_runtime.h>
#include <hip/hip_bf16.h>
#include <math.h>

#define XKP 1216

typedef unsigned short u16;
typedef short bf16x8 __attribute__((ext_vector_type(8)));
typedef u16 ushort8 __attribute__((ext_vector_type(8)));
typedef float f32x4 __attribute__((ext_vector_type(4)));

static __device__ __forceinline__ float sigmoidf_(float x){ return 1.f/(1.f+expf(-x)); }
static __device__ __forceinline__ u16 f2bf(float x){ __hip_bfloat16 h = __float2bfloat16(x); return *reinterpret_cast<u16*>(&h); }
static __device__ __forceinline__ float bf2f(u16 u){ __hip_bfloat16 h; *reinterpret_cast<u16*>(&h) = u; return __bfloat162float(h); }
static __device__ __forceinline__ float bfb(u16 u){ return __uint_as_float(((unsigned)u) << 16); }

// ---------- generic 32x32 tiled transpose ----------
__global__ __launch_bounds__(256) void k_transpose(const float* __restrict__ in,
                                                   float* __restrict__ out, int R, int C) {
  __shared__ float tile[32][33];
  int c0 = blockIdx.x * 32, r0 = blockIdx.y * 32;
  int tx = threadIdx.x & 31, ty = threadIdx.x >> 5;
  for (int i = 0; i < 32; i += 8) {
    int r = r0 + ty + i, c = c0 + tx;
    tile[ty + i][tx] = (r < R && c < C) ? in[(size_t)r * C + c] : 0.f;
  }
  __syncthreads();
  for (int i = 0; i < 32; i += 8) {
    int c = c0 + ty + i, r = r0 + tx;
    if (c < C && r < R) out[(size_t)c * R + r] = tile[tx][ty + i];
  }
}

// ---------- fp32 -> bf16 ----------
__global__ __launch_bounds__(256) void k_cvt(const float* __restrict__ in,
                                             u16* __restrict__ out, int n) {
  for (int i = blockIdx.x * 256 + threadIdx.x; i < n; i += gridDim.x * 256)
    out[i] = f2bf(in[i]);
}

// ---------- Wcat split hi/lo, gate-interleaved: row n'=d*4+g <- j=g*512+d ----------
__global__ __launch_bounds__(256) void k_wcat_split(const float* __restrict__ W_ih,
                                                    const float* __restrict__ W_hh,
                                                    u16* __restrict__ Whi,
                                                    u16* __restrict__ Wlo) {
  int np = blockIdx.x;
  int d = np >> 2, g = np & 3;
  int j = g * 512 + d;
  for (int c = threadIdx.x; c < XKP; c += 256) {
    float v;
    if (c < 684)        v = W_ih[(size_t)j * 684 + c];
    else if (c < 1196)  v = W_hh[(size_t)j * 512 + (c - 684)];
    else                v = 0.f;
    u16 hi = f2bf(v);
    u16 lo = f2bf(v - bf2f(hi));
    Whi[(size_t)np * XKP + c] = hi;
    Wlo[(size_t)np * XKP + c] = lo;
  }
}

// ---------- objectness mask + top-16 + enc mean ----------
__global__ __launch_bounds__(128) void k_mask(const float* __restrict__ objs,
                                              const float* __restrict__ rcl,
                                              const float* __restrict__ avx,
                                              const float* __restrict__ enc,
                                              float* __restrict__ maskf,
                                              float* __restrict__ encmean,
                                              float* __restrict__ out_mask) {
  int b = blockIdx.x, k = threadIdx.x;
  __shared__ float dsh[128];
  __shared__ float maxd;
  float s0 = objs[(size_t)(b * 128 + k) * 2 + 0];
  float s1 = objs[(size_t)(b * 128 + k) * 2 + 1];
  float mx = fmaxf(s0, s1);
  float e0 = expf(s0 - mx), e1 = expf(s1 - mx);
  float p  = e1 / (e0 + e1);
  bool om  = p > 0.75f;
  float dx = rcl[b * 3 + 0] - avx[(size_t)(b * 128 + k) * 3 + 0];
  float dy = rcl[b * 3 + 1] - avx[(size_t)(b * 128 + k) * 3 + 1];
  float dz = rcl[b * 3 + 2] - avx[(size_t)(b * 128 + k) * 3 + 2];
  float dist = sqrtf(dx * dx + dy * dy + dz * dz);
  float dm = om ? dist : INFINITY;
  dsh[k] = dm;
  __syncthreads();
  float v = dm; int clt = 0, cle = 0;
  for (int j = 0; j < 128; j++) { float o = dsh[j]; clt += (o < v); cle += (o <= v); }
  if (clt < 16 && cle >= 16) maxd = v;
  __syncthreads();
  bool msk = om && (dm <= maxd);
  maskf[b * 128 + k]    = msk ? 1.f : 0.f;
  out_mask[b * 128 + k] = msk ? 1.f : 0.f;
  float s = 0.f;
  for (int kk = 0; kk < 128; kk++) s += enc[(size_t)(b * 128 + kk) * 128 + k];
  encmean[b * 128 + k] = s * (1.f / 128.f);
}

// ---------- h0/c0 init ----------
__global__ __launch_bounds__(512) void k_init(const float* __restrict__ encm,
                                              const float* __restrict__ rof,
                                              const float* __restrict__ wihT,
                                              const float* __restrict__ wicT,
                                              const float* __restrict__ bh,
                                              const float* __restrict__ bc,
                                              float* __restrict__ h, float* __restrict__ c) {
  int b = blockIdx.x, d = threadIdx.x;
  __shared__ float xin[384];
  if (d < 128) xin[d] = encm[b * 128 + d];
  else if (d < 384) xin[d] = rof[(size_t)b * 256 + (d - 128)];
  __syncthreads();
  float ah = bh[d], ac = bc[d];
  for (int i = 0; i < 384; i++) {
    float x = xin[i];
    ah += x * wihT[(size_t)i * 512 + d];
    ac += x * wicT[(size_t)i * 512 + d];
  }
  size_t idx = (size_t)b * 512 + d;
  h[idx] = ah;
  c[idx] = ac;
}

// ---------- att1 via MFMA -> bf16 out ----------
__global__ __launch_bounds__(256) void k_att1m(const u16* __restrict__ enc16,
                                               const u16* __restrict__ We16,
                                               const float* __restrict__ b_enc,
                                               u16* __restrict__ att1b) {
  int w = threadIdx.x >> 6, lane = threadIdx.x & 63;
  int gw = blockIdx.x * 4 + w;
  int nt = gw & 15, mt = gw >> 4;
  int m0 = mt * 32, n0 = nt * 32;
  int rc = lane & 15, kb = lane >> 4;
  const bf16x8* a0 = (const bf16x8*)(enc16 + (size_t)(m0 + rc) * 128) + kb;
  const bf16x8* a1 = (const bf16x8*)(enc16 + (size_t)(m0 + 16 + rc) * 128) + kb;
  const bf16x8* b0 = (const bf16x8*)(We16 + (size_t)(n0 + rc) * 128) + kb;
  const bf16x8* b1 = (const bf16x8*)(We16 + (size_t)(n0 + 16 + rc) * 128) + kb;
  f32x4 z = {0.f, 0.f, 0.f, 0.f};
  f32x4 acc00 = z, acc01 = z, acc10 = z, acc11 = z;
#pragma unroll
  for (int kk = 0; kk < 4; kk++) {
    bf16x8 av0 = a0[kk * 4], av1 = a1[kk * 4];
    bf16x8 bv0 = b0[kk * 4], bv1 = b1[kk * 4];
    acc00 = __builtin_amdgcn_mfma_f32_16x16x32_bf16(av0, bv0, acc00, 0, 0, 0);
    acc01 = __builtin_amdgcn_mfma_f32_16x16x32_bf16(av0, bv1, acc01, 0, 0, 0);
    acc10 = __builtin_amdgcn_mfma_f32_16x16x32_bf16(av1, bv0, acc10, 0, 0, 0);
    acc11 = __builtin_amdgcn_mfma_f32_16x16x32_bf16(av1, bv1, acc11, 0, 0, 0);
  }
  int col = lane & 15, rbase = (lane >> 4) * 4;
#pragma unroll
  for (int r = 0; r < 4; r++) {
    int r0g = m0 + rbase + r;
    att1b[(size_t)r0g * 512 + n0 + col]             = f2bf(acc00[r] + b_enc[n0 + col]);
    att1b[(size_t)r0g * 512 + n0 + 16 + col]        = f2bf(acc01[r] + b_enc[n0 + 16 + col]);
    att1b[(size_t)(r0g + 16) * 512 + n0 + col]      = f2bf(acc10[r] + b_enc[n0 + col]);
    att1b[(size_t)(r0g + 16) * 512 + n0 + 16 + col] = f2bf(acc11[r] + b_enc[n0 + 16 + col]);
  }
}

// ---------- per-step attention + softmax + awe + gate + X build (128 blocks x 512) ----------
__global__ __launch_bounds__(512) void k_step(
    const u16* __restrict__ att1b, const float* __restrict__ hbuf,
    const float* __restrict__ wdT, const float* __restrict__ b_dec,
    const float* __restrict__ wfull, const float* __restrict__ bfull,
    const u16* __restrict__ enc16, const float* __restrict__ maskf,
    const float* __restrict__ wfbT, const float* __restrict__ b_fb,
    const float* __restrict__ rof, const float* __restrict__ embt,
    const float* __restrict__ iemb, const int* __restrict__ lidx,
    const int* __restrict__ llen, u16* __restrict__ Xhi, u16* __restrict__ Xlo,
    float* __restrict__ alphas_out, int t) {
  const int tid = threadIdx.x;
  const int w = tid >> 6, lane = tid & 63;
  const int b = blockIdx.x;

  __shared__ float hs[512], a2s[512], wf[512];
  __shared__ float attk[128], alph[128], awes[128];
  __shared__ float red1[8], red2[8];

  hs[tid] = hbuf[(size_t)b * 512 + tid];
  wf[tid] = wfull[tid];
  __syncthreads();
  // att2[a] = h . W_dec[a,:] + b_dec (4-acc)
  {
    float ac0 = 0.f, ac1 = 0.f, ac2 = 0.f, ac3 = 0.f;
    for (int i = 0; i < 512; i += 4) {
      ac0 += hs[i + 0] * wdT[(size_t)(i + 0) * 512 + tid];
      ac1 += hs[i + 1] * wdT[(size_t)(i + 1) * 512 + tid];
      ac2 += hs[i + 2] * wdT[(size_t)(i + 2) * 512 + tid];
      ac3 += hs[i + 3] * wdT[(size_t)(i + 3) * 512 + tid];
    }
    a2s[tid] = (ac0 + ac1) + (ac2 + ac3) + b_dec[tid];
  }
  __syncthreads();
  // att[k] = relu(att1+att2).wfull (4 threads per k, bf16 att1)
  int k = tid >> 2, j = tid & 3;
  {
    const ushort8* a1 = (const ushort8*)(att1b + (size_t)(b * 128 + k) * 512 + j * 128);
    float s = 0.f;
#pragma unroll 2
    for (int i = 0; i < 16; i++) {
      ushort8 v = a1[i];
      int base = j * 128 + i * 8;
#pragma unroll
      for (int e = 0; e < 8; e++)
        s += fmaxf(bfb(v[e]) + a2s[base + e], 0.f) * wf[base + e];
    }
    s += __shfl_xor(s, 1);
    s += __shfl_xor(s, 2);
    if (j == 0) attk[k] = s + bfull[0];
  }
  __syncthreads();
  // masked softmax over K=128
  float mk = 0.f, av = 0.f;
  if (tid < 128) { mk = maskf[b * 128 + tid]; av = attk[tid]; }
  float nv = (tid < 128 && mk != 0.f) ? av : -INFINITY;
  float wm = nv;
#pragma unroll
  for (int o = 32; o > 0; o >>= 1) wm = fmaxf(wm, __shfl_xor(wm, o));
  if (tid < 128 && lane == 0) red1[w] = wm;
  __syncthreads();
  float m = fmaxf(red1[0], red1[1]);
  float e = (tid < 128 && mk != 0.f) ? expf(av - m) : 0.f;
  float sr = e;
#pragma unroll
  for (int o = 32; o > 0; o >>= 1) sr += __shfl_xor(sr, o);
  if (tid < 128 && lane == 0) red2[w] = sr;
  __syncthreads();
  float dsum = red2[0] + red2[1];
  float alpha = (dsum > 0.f) ? e / fmaxf(dsum, 1e-30f) : 0.f;
  int active = t < llen[b];
  if (tid < 128) {
    alph[tid] = alpha;
    alphas_out[(size_t)(b * 32 + t) * 128 + tid] = active ? alpha : 0.f;
  }
  __syncthreads();
  // gate[v] + awe[v] (4 threads per v)
  {
    int v = tid >> 2;
    float g = 0.f;
    for (int ii = 0; ii < 128; ii++) {
      int i = j * 128 + ii;
      g += hs[i] * wfbT[(size_t)i * 128 + v];
    }
    g += __shfl_xor(g, 1);
    g += __shfl_xor(g, 2);
    float gate = sigmoidf_(g + b_fb[v]);
    float aw = 0.f;
    for (int kk = j * 32; kk < j * 32 + 32; kk++)
      aw += alph[kk] * bfb(enc16[(size_t)(b * 128 + kk) * 128 + v]);
    aw += __shfl_xor(aw, 1);
    aw += __shfl_xor(aw, 2);
    if (j == 0) awes[v] = aw * gate;
  }
  __syncthreads();
  // X row b -> bf16 hi/lo
  const float* esrc = (t == 0) ? iemb : (embt + (size_t)lidx[b * 32 + (t - 1)] * 300);
  for (int c = tid; c < XKP; c += 512) {
    float val;
    if (c < 300)       val = esrc[c];
    else if (c < 428)  val = awes[c - 300];
    else if (c < 684)  val = rof[(size_t)b * 256 + (c - 428)];
    else if (c < 1196) val = hs[c - 684];
    else               val = 0.f;
    u16 hi = f2bf(val);
    Xhi[(size_t)b * XKP + c] = hi;
    Xlo[(size_t)b * XKP + c] = f2bf(val - bf2f(hi));
  }
}

// ---------- gates GEMM + LSTM (256 blocks x 256 thr; block = (np, half)) ----------
__global__ __launch_bounds__(256) void k_gates2(const u16* __restrict__ Xhi,
                                                const u16* __restrict__ Xlo,
                                                const u16* __restrict__ WcatHi,
                                                const u16* __restrict__ WcatLo,
                                                const float* __restrict__ b_ih,
                                                const float* __restrict__ b_hh,
                                                const int* __restrict__ llen,
                                                float* __restrict__ hbuf,
                                                float* __restrict__ cbuf,
                                                u16* __restrict__ hball, int t) {
  const int w = threadIdx.x >> 6, lane = threadIdx.x & 63;
  const int rc = lane & 15, kb = lane >> 4;
  const int np = blockIdx.x >> 1;                 // n'-tile 0..127
  const int mg = (blockIdx.x & 1) * 4 + w;        // m-tile 0..7
  int m0 = mg * 16, n0 = np * 16;
  const bf16x8* aHi = (const bf16x8*)(Xhi + (size_t)(m0 + rc) * XKP) + kb;
  const bf16x8* aLo = (const bf16x8*)(Xlo + (size_t)(m0 + rc) * XKP) + kb;
  const bf16x8* bHi = (const bf16x8*)(WcatHi + (size_t)(n0 + rc) * XKP) + kb;
  const bf16x8* bLo = (const bf16x8*)(WcatLo + (size_t)(n0 + rc) * XKP) + kb;
  f32x4 acc = {0.f, 0.f, 0.f, 0.f};
#pragma unroll 2
  for (int kk = 0; kk < 38; kk++) {
    bf16x8 ah = aHi[kk * 4], al = aLo[kk * 4];
    bf16x8 bh = bHi[kk * 4], bl = bLo[kk * 4];
    acc = __builtin_amdgcn_mfma_f32_16x16x32_bf16(ah, bh, acc, 0, 0, 0);
    acc = __builtin_amdgcn_mfma_f32_16x16x32_bf16(al, bh, acc, 0, 0, 0);
    acc = __builtin_amdgcn_mfma_f32_16x16x32_bf16(ah, bl, acc, 0, 0, 0);
  }
  // LSTM via intra-wave shfl: lanes 4q..4q+3 hold gates 0..3 of d=np*4+q
  int col = lane & 15;
  int d = np * 4 + (col >> 2);
  int baseL = lane & ~3;
#pragma unroll
  for (int r = 0; r < 4; r++) {
    int bb = m0 + (lane >> 4) * 4 + r;
    float g0 = __shfl(acc[r], baseL + 0);
    float g1 = __shfl(acc[r], baseL + 1);
    float g2 = __shfl(acc[r], baseL + 2);
    float g3 = __shfl(acc[r], baseL + 3);
    if ((lane & 3) == 0 && t < llen[bb]) {
      float i_ = sigmoidf_(g0 + b_ih[d]        + b_hh[d]);
      float f_ = sigmoidf_(g1 + b_ih[512 + d]  + b_hh[512 + d]);
      float gg = tanhf   (g2 + b_ih[1024 + d] + b_hh[1024 + d]);
      float o_ = sigmoidf_(g3 + b_ih[1536 + d] + b_hh[1536 + d]);
      size_t idx = (size_t)bb * 512 + d;
      float cn = f_ * cbuf[idx] + i_ * gg;
      float hn = o_ * tanhf(cn);
      cbuf[idx] = cn;
      hbuf[idx] = hn;
      hball[((size_t)t * 128 + bb) * 512 + d] = f2bf(hn);
    }
  }
}

// ---------- deferred fc over all timesteps: rows = t*128+b (M=4096), N=4000 ----------
__global__ __launch_bounds__(256) void k_fc_def(const u16* __restrict__ hball,
                                                const u16* __restrict__ Wfc16,
                                                const float* __restrict__ b_fc,
                                                const int* __restrict__ llen,
                                                float* __restrict__ dst, int direct) {
  const int w = threadIdx.x >> 6, lane = threadIdx.x & 63;
  const int rc = lane & 15, kb = lane >> 4;
  int nb = blockIdx.x;                // 0..249
  int n0 = nb * 16;
  const bf16x8* bP = (const bf16x8*)(Wfc16 + (size_t)(n0 + rc) * 512) + kb;
#pragma unroll
  for (int s = 0; s < 2; s++) {
    int mtile = blockIdx.y * 8 + w * 2 + s;   // 0..255
    int m0 = mtile * 16;
    const bf16x8* aP = (const bf16x8*)(hball + (size_t)(m0 + rc) * 512) + kb;
    f32x4 acc = {0.f, 0.f, 0.f, 0.f};
#pragma unroll
    for (int kk = 0; kk < 16; kk++)
      acc = __builtin_amdgcn_mfma_f32_16x16x32_bf16(aP[kk * 4], bP[kk * 4], acc, 0, 0, 0);
    int col = lane & 15, rb = (lane >> 4) * 4;
    int v = n0 + col;
    float bias = b_fc[v];
#pragma unroll
    for (int r = 0; r < 4; r++) {
      int gr = m0 + rb + r;                   // global row = t*128 + b
      int t = gr >> 7, bb = gr & 127;
      float val = (t < llen[bb]) ? (acc[r] + bias) : 0.f;
      if (direct) dst[((size_t)bb * 4000 + v) * 32 + t] = val;
      else        dst[(size_t)gr * 4000 + v] = val;
    }
  }
}

// ---------- final transpose predsT[T,B,V] -> out[B,V,T] ----------
__global__ __launch_bounds__(256) void k_out_tr(const float* __restrict__ predsT,
                                                float* __restrict__ out) {
  __shared__ float tile[32][33];
  int b = blockIdx.y, v0 = blockIdx.x * 32;
  int tx = threadIdx.x & 31, ty = threadIdx.x >> 5;
  for (int i = 0; i < 32; i += 8) {
    int tt = ty + i;
    tile[tt][tx] = predsT[((size_t)tt * 128 + b) * 4000 + v0 + tx];
  }
  __syncthreads();
  for (int i = 0; i < 32; i += 8) {
    int v = v0 + ty + i;
    out[((size_t)b * 4000 + v) * 32 + tx] = tile[tx][ty + i];
  }
}

extern "C" void kernel_launch(void* const* d_in, const int* in_sizes, int n_in,
                              void* d_out, int out_size, void* d_ws, size_t ws_size,
                              hipStream_t stream) {
  (void)in_sizes; (void)n_in; (void)out_size;
  const float* avf   = (const float*)d_in[0];
  const float* rof   = (const float*)d_in[1];
  const float* objs  = (const float*)d_in[2];
  const float* rcl   = (const float*)d_in[3];
  const float* avx   = (const float*)d_in[4];
  const int*   lidx  = (const int*)d_in[5];
  const int*   llen  = (const int*)d_in[6];
  const float* embt  = (const float*)d_in[7];
  const float* iemb  = (const float*)d_in[8];
  const float* W_enc = (const float*)d_in[9];
  const float* b_enc = (const float*)d_in[10];
  const float* W_dec = (const float*)d_in[11];
  const float* b_dec = (const float*)d_in[12];
  const float* wfull = (const float*)d_in[13];
  const float* bfull = (const float*)d_in[14];
  const float* W_ih  = (const float*)d_in[15];
  const float* b_ih  = (const float*)d_in[16];
  const float* W_hh  = (const float*)d_in[17];
  const float* b_hh  = (const float*)d_in[18];
  const float* W_inh = (const float*)d_in[19];
  const float* b_inh = (const float*)d_in[20];
  const float* W_inc = (const float*)d_in[21];
  const float* b_inc = (const float*)d_in[22];
  const float* W_fb  = (const float*)d_in[23];
  const float* b_fb  = (const float*)d_in[24];
  const float* W_fc  = (const float*)d_in[25];
  const float* b_fc  = (const float*)d_in[26];

  float* ws = (float*)d_ws;
  size_t f = 0;
  auto A8 = [&](size_t n) { size_t o = f; f += (n + 63) & ~(size_t)63; return o; };
  u16*   att1b = (u16*)(ws + A8((size_t)16384 * 512 / 2));
  float* wdT   = ws + A8(512 * 512);
  float* wihT  = ws + A8(384 * 512);
  float* wicT  = ws + A8(384 * 512);
  float* wfbT  = ws + A8(512 * 128);
  float* hbuf  = ws + A8(128 * 512);
  float* cbuf  = ws + A8(128 * 512);
  float* maskf = ws + A8(128 * 128);
  float* encm  = ws + A8(128 * 128);
  u16*   Xhi   = (u16*)(ws + A8((size_t)128 * XKP / 2));
  u16*   Xlo   = (u16*)(ws + A8((size_t)128 * XKP / 2));
  u16*   WcatHi= (u16*)(ws + A8((size_t)2048 * XKP / 2));
  u16*   WcatLo= (u16*)(ws + A8((size_t)2048 * XKP / 2));
  u16*   enc16 = (u16*)(ws + A8((size_t)128 * 128 * 128 / 2));
  u16*   We16  = (u16*)(ws + A8((size_t)512 * 128 / 2));
  u16*   Wfc16 = (u16*)(ws + A8((size_t)4000 * 512 / 2));
  u16*   hball = (u16*)(ws + A8((size_t)32 * 128 * 512 / 2));
  float* predsT= ws + A8((size_t)32 * 128 * 4000);
  bool useT = ws_size >= f * sizeof(float);

  float* out_pred  = (float*)d_out;
  float* out_alpha = out_pred + (size_t)16384000;
  float* out_mask  = out_alpha + (size_t)524288;

  // ---- setup ----
  k_transpose<<<dim3(16, 16), 256, 0, stream>>>(W_dec, wdT, 512, 512);
  k_transpose<<<dim3(12, 16), 256, 0, stream>>>(W_inh, wihT, 512, 384);
  k_transpose<<<dim3(12, 16), 256, 0, stream>>>(W_inc, wicT, 512, 384);
  k_transpose<<<dim3(16, 4),  256, 0, stream>>>(W_fb, wfbT, 128, 512);
  k_wcat_split<<<2048, 256, 0, stream>>>(W_ih, W_hh, WcatHi, WcatLo);
  k_cvt<<<2048, 256, 0, stream>>>(avf, enc16, 128 * 128 * 128);
  k_cvt<<<256,  256, 0, stream>>>(W_enc, We16, 512 * 128);
  k_cvt<<<2048, 256, 0, stream>>>(W_fc, Wfc16, 4000 * 512);
  k_mask<<<128, 128, 0, stream>>>(objs, rcl, avx, avf, maskf, encm, out_mask);
  k_init<<<128, 512, 0, stream>>>(encm, rof, wihT, wicT, b_inh, b_inc, hbuf, cbuf);
  k_att1m<<<2048, 256, 0, stream>>>(enc16, We16, b_enc, att1b);

  // ---- decode loop: 2 dispatches/step ----
  for (int t = 0; t < 32; t++) {
    k_step<<<128, 512, 0, stream>>>(att1b, hbuf, wdT, b_dec, wfull, bfull,
        enc16, maskf, wfbT, b_fb, rof, embt, iemb, lidx, llen, Xhi, Xlo, out_alpha, t);
    k_gates2<<<256, 256, 0, stream>>>(Xhi, Xlo, WcatHi, WcatLo, b_ih, b_hh, llen,
                                      hbuf, cbuf, hball, t);
  }

  // ---- deferred fc + transpose ----
  k_fc_def<<<dim3(250, 32), 256, 0, stream>>>(hball, Wfc16, b_fc, llen,
                                              useT ? predsT : out_pred, useT ? 0 : 1);
  if (useT) k_out_tr<<<dim3(125, 128), 256, 0, stream>>>(predsT, out_pred);
}